// Round 1
// baseline (453.013 us; speedup 1.0000x reference)
//
#include <hip/hip_runtime.h>

#define N_V  20000
#define B_   8
#define F_   64
#define K_   6
#define OUT_ 64
#define NNZ_ 320000
#define BF   512    // B_*F_
#define NBUK N_V                    // one bucket per row
#define SCANB 20                    // ceil(NBUK/1024)
#define EPAD (NNZ_ + N_V * 7)       // max padded edges (pad each row to mult of 8)

typedef unsigned short ushort_t;
typedef unsigned int   uint_t;

using frag_ab = __attribute__((ext_vector_type(8))) short;  // 8 bf16 (4 VGPRs)
using frag_cd = __attribute__((ext_vector_type(4))) float;  // 4 f32 acc

// ---- bf16 helpers ----
__device__ __forceinline__ ushort_t f2bf(float f) {          // round-to-nearest-even
    uint_t u = __float_as_uint(f);
    u += 0x7FFFu + ((u >> 16) & 1u);
    return (ushort_t)(u >> 16);
}
__device__ __forceinline__ uint_t pack2(float lo, float hi) {
    return (uint_t)f2bf(lo) | ((uint_t)f2bf(hi) << 16);
}
__device__ __forceinline__ float bf2f(ushort_t u) {
    return __uint_as_float((uint_t)u << 16);
}

// -------- bucketed build: one bucket per row, padded to multiple of 8 --------

__global__ void hist_kernel(const int* __restrict__ rows, int* __restrict__ counts) {
    int e = blockIdx.x * 256 + threadIdx.x;
    if (e < NNZ_) atomicAdd(&counts[rows[e]], 1);
}

__global__ __launch_bounds__(1024) void scan1(const int* __restrict__ counts,
                                              int* __restrict__ incl, int* __restrict__ bsum) {
    __shared__ int buf[1024];
    int tid = threadIdx.x;
    int i = blockIdx.x * 1024 + tid;
    int c = (i < NBUK) ? ((counts[i] + 7) & ~7) : 0;   // padded count
    buf[tid] = c;
    __syncthreads();
    for (int off = 1; off < 1024; off <<= 1) {
        int t = buf[tid];
        int add = (tid >= off) ? buf[tid - off] : 0;
        __syncthreads();
        buf[tid] = t + add;
        __syncthreads();
    }
    if (i < NBUK) incl[i] = buf[tid];
    if (tid == 1023) bsum[blockIdx.x] = buf[1023];
}

__global__ __launch_bounds__(256) void scan2(int* __restrict__ bsum) {
    __shared__ int buf[256];
    int tid = threadIdx.x;
    int c = (tid < SCANB) ? bsum[tid] : 0;
    buf[tid] = c;
    __syncthreads();
    for (int off = 1; off < 256; off <<= 1) {
        int t = buf[tid];
        int add = (tid >= off) ? buf[tid - off] : 0;
        __syncthreads();
        buf[tid] = t + add;
        __syncthreads();
    }
    if (tid < SCANB) bsum[tid] = buf[tid] - c;   // exclusive block offsets
}

__global__ __launch_bounds__(1024) void scan3(const int* __restrict__ counts,
                                              const int* __restrict__ bsum,
                                              int* __restrict__ bp, int* __restrict__ cursor) {
    int tid = threadIdx.x;
    int i = blockIdx.x * 1024 + tid;
    if (i < NBUK) {
        int pc = (counts[i] + 7) & ~7;
        int p = bsum[blockIdx.x] + cursor[i];   // global inclusive prefix (padded)
        bp[i + 1] = p;
        cursor[i] = p - pc;                     // bucket start for scatter
    }
    if (i == 0) bp[0] = 0;
}

// edges packed: {col, val_bits}; pad slots stay {0, 0.0f} from memset (zero contribution)
__global__ void scatter_kernel(const int* __restrict__ rows, const int* __restrict__ cols,
                               const float* __restrict__ vals, int* __restrict__ cursor,
                               int2* __restrict__ edges) {
    int e = blockIdx.x * 256 + threadIdx.x;
    if (e < NNZ_) {
        int pos = atomicAdd(&cursor[rows[e]], 1);
        edges[pos] = make_int2(cols[e], __float_as_int(vals[e]));
    }
}

// ---------------- fat prep: x->X0 bf16 (T layout [n][b][f]) + Wfrag pack ----------------
__global__ void prep_kernel(const float* __restrict__ x, uint_t* __restrict__ X0,
                            const float* __restrict__ W, ushort_t* __restrict__ Wfrag) {
    int blk = blockIdx.x;
    if (blk < 20000) {
        int idx = blk * 256 + threadIdx.x;      // over N_V*B_*32
        int f2 = idx & 31;
        int b  = (idx >> 5) & 7;
        int n  = idx >> 8;
        float2 v = *(const float2*)&x[((size_t)b * N_V + n) * F_ + f2 * 2];
        X0[n * 256 + b * 32 + f2] = pack2(v.x, v.y);
    } else {
        int idx = (blk - 20000) * 256 + threadIdx.x;
        if (idx < 12 * 4 * 64 * 8) {
            int j    = idx & 7;
            int lane = (idx >> 3) & 63;
            int ct   = (idx >> 9) & 3;
            int s    = idx >> 11;
            int o     = ct * 16 + (lane & 15);
            int kglob = s * 32 + ((lane >> 4) & 3) * 8 + j;
            Wfrag[idx] = f2bf(W[o * (K_ * F_) + kglob]);
        }
    }
}

// -------- SpMM: one wave per (row, batch-chunk); chunk = blockIdx%8 -> XCD affinity --------
// Per-XCD gather footprint = N_V * 64 bf16 = 2.56 MB  -> fits a 4 MB XCD L2.
// lane = feature within chunk; gather = 64 lanes x 2B = one 128B contiguous transaction.
// Edge stream is padded to a multiple of 8 with {col=0, val=0} -> no bounds logic.
template <bool RECUR>
__global__ __launch_bounds__(256) void cheb_row(const int* __restrict__ bp,
                                                const int2* __restrict__ edges,
                                                const ushort_t* __restrict__ Tprev,
                                                const ushort_t* __restrict__ Tpp,
                                                ushort_t* __restrict__ Tout) {
    const int wave = __builtin_amdgcn_readfirstlane(threadIdx.x >> 6);
    const int lane = threadIdx.x & 63;
    const int c    = blockIdx.x & 7;                 // chunk == batch index == XCD slot
    const int row  = ((blockIdx.x >> 3) << 2) + wave;

    const int st = bp[row];                          // uniform (SGPR) -> s_load
    const int en = bp[row + 1];
    const ushort_t* Tp = Tprev + (c << 6) + lane;

    float a0 = 0.f, a1 = 0.f;
    for (int j = st; j < en; j += 8) {
        const int4* e4 = (const int4*)(edges + j);   // 64B-aligned, uniform
        int4 E0 = e4[0], E1 = e4[1], E2 = e4[2], E3 = e4[3];
        // force edge decode + gather base onto the scalar path
        const int c0 = __builtin_amdgcn_readfirstlane(E0.x);
        const int c1 = __builtin_amdgcn_readfirstlane(E0.z);
        const int c2 = __builtin_amdgcn_readfirstlane(E1.x);
        const int c3 = __builtin_amdgcn_readfirstlane(E1.z);
        const int c4 = __builtin_amdgcn_readfirstlane(E2.x);
        const int c5 = __builtin_amdgcn_readfirstlane(E2.z);
        const int c6 = __builtin_amdgcn_readfirstlane(E3.x);
        const int c7 = __builtin_amdgcn_readfirstlane(E3.z);
        const float v0 = __int_as_float(__builtin_amdgcn_readfirstlane(E0.y));
        const float v1 = __int_as_float(__builtin_amdgcn_readfirstlane(E0.w));
        const float v2 = __int_as_float(__builtin_amdgcn_readfirstlane(E1.y));
        const float v3 = __int_as_float(__builtin_amdgcn_readfirstlane(E1.w));
        const float v4 = __int_as_float(__builtin_amdgcn_readfirstlane(E2.y));
        const float v5 = __int_as_float(__builtin_amdgcn_readfirstlane(E2.w));
        const float v6 = __int_as_float(__builtin_amdgcn_readfirstlane(E3.y));
        const float v7 = __int_as_float(__builtin_amdgcn_readfirstlane(E3.w));

        ushort_t t0 = Tp[(size_t)c0 << 9];
        ushort_t t1 = Tp[(size_t)c1 << 9];
        ushort_t t2 = Tp[(size_t)c2 << 9];
        ushort_t t3 = Tp[(size_t)c3 << 9];
        ushort_t t4 = Tp[(size_t)c4 << 9];
        ushort_t t5 = Tp[(size_t)c5 << 9];
        ushort_t t6 = Tp[(size_t)c6 << 9];
        ushort_t t7 = Tp[(size_t)c7 << 9];

        a0 = fmaf(v0, bf2f(t0), a0);
        a1 = fmaf(v1, bf2f(t1), a1);
        a0 = fmaf(v2, bf2f(t2), a0);
        a1 = fmaf(v3, bf2f(t3), a1);
        a0 = fmaf(v4, bf2f(t4), a0);
        a1 = fmaf(v5, bf2f(t5), a1);
        a0 = fmaf(v6, bf2f(t6), a0);
        a1 = fmaf(v7, bf2f(t7), a1);
    }

    float res = a0 + a1;
    const size_t oidx = (size_t)row * BF + (c << 6) + lane;
    if (RECUR) {
        res = fmaf(2.f, res, -bf2f(Tpp[oidx]));      // T_k = 2*L*T_{k-1} - T_{k-2}
    }
    Tout[oidx] = f2bf(res);
}

// ---------------- FC via MFMA 16x16x32 bf16, 2 tiles/wave ----------------
__global__ __launch_bounds__(256) void fc_mfma(const ushort_t* __restrict__ X0,
                                               const ushort_t* __restrict__ T1,
                                               const ushort_t* __restrict__ T2,
                                               const ushort_t* __restrict__ T3,
                                               const ushort_t* __restrict__ T4,
                                               const ushort_t* __restrict__ T5,
                                               const ushort_t* __restrict__ Wfrag,
                                               const float* __restrict__ bias,
                                               float* __restrict__ out) {
    const int wave = threadIdx.x >> 6, lane = threadIdx.x & 63;
    const int quad = lane >> 4, col = lane & 15;
    const int tb = blockIdx.x * 128 + wave * 32;      // 2 tiles: tb, tb+16
    const int r0 = tb + col, r1 = tb + 16 + col;
    const ushort_t* Tbuf[6] = {X0, T1, T2, T3, T4, T5};

    frag_cd acc0[4], acc1[4];
#pragma unroll
    for (int ct = 0; ct < 4; ++ct) {
        acc0[ct] = (frag_cd){0.f, 0.f, 0.f, 0.f};
        acc1[ct] = (frag_cd){0.f, 0.f, 0.f, 0.f};
    }

#pragma unroll
    for (int s = 0; s < 12; ++s) {
        const int f0 = (s & 1) * 32 + quad * 8;
        frag_ab fa0 = *(const frag_ab*)(Tbuf[s >> 1] + (size_t)r0 * F_ + f0);
        frag_ab fa1 = *(const frag_ab*)(Tbuf[s >> 1] + (size_t)r1 * F_ + f0);
#pragma unroll
        for (int ct = 0; ct < 4; ++ct) {
            frag_ab bfr = *(const frag_ab*)(Wfrag + (((s * 4 + ct) * 64 + lane) << 3));
            acc0[ct] = __builtin_amdgcn_mfma_f32_16x16x32_bf16(fa0, bfr, acc0[ct], 0, 0, 0);
            acc1[ct] = __builtin_amdgcn_mfma_f32_16x16x32_bf16(fa1, bfr, acc1[ct], 0, 0, 0);
        }
    }

    // C/D: col = lane&15, row = quad*4 + reg
#pragma unroll
    for (int ct = 0; ct < 4; ++ct) {
        const int o = ct * 16 + col;
        const float bv = bias[o];
#pragma unroll
        for (int reg = 0; reg < 4; ++reg) {
            int ra = tb + quad * 4 + reg;
            int rb = ra + 16;
            out[(size_t)(ra & 7) * N_V * OUT_ + (size_t)(ra >> 3) * OUT_ + o] = acc0[ct][reg] + bv;
            out[(size_t)(rb & 7) * N_V * OUT_ + (size_t)(rb >> 3) * OUT_ + o] = acc1[ct][reg] + bv;
        }
    }
}

// ---------------- launcher ----------------

extern "C" void kernel_launch(void* const* d_in, const int* in_sizes, int n_in,
                              void* d_out, int out_size, void* d_ws, size_t ws_size,
                              hipStream_t stream) {
    const float* x    = (const float*)d_in[0];
    const int*   rows = (const int*)  d_in[1];
    const int*   cols = (const int*)  d_in[2];
    const float* vals = (const float*)d_in[3];
    const float* W    = (const float*)d_in[4];
    const float* bias = (const float*)d_in[5];
    float* out = (float*)d_out;

    const size_t TSZ = (size_t)N_V * BF;           // bf16 elements per T buffer
    ushort_t* T1 = (ushort_t*)d_ws;
    ushort_t* T2 = T1 + TSZ;
    ushort_t* T3 = T2 + TSZ;
    ushort_t* T4 = T3 + TSZ;
    ushort_t* T5 = T4 + TSZ;
    ushort_t* X0 = T5 + TSZ;
    ushort_t* Wfrag = X0 + TSZ;                    // 24576 ushorts
    int* counts    = (int*)(Wfrag + 24576);        // NBUK
    int* bp        = counts + NBUK;                // NBUK+1 (+pad)
    int* cursor    = bp + NBUK + 64;               // NBUK
    int* bsum      = cursor + NBUK;                // 256
    int2* edges    = (int2*)(bsum + 256);          // EPAD int2 (zero-padded)

    hipMemsetAsync(counts, 0, NBUK * sizeof(int), stream);
    hipMemsetAsync(edges, 0, (size_t)EPAD * sizeof(int2), stream);
    hist_kernel<<<(NNZ_ + 255) / 256, 256, 0, stream>>>(rows, counts);
    scan1<<<SCANB, 1024, 0, stream>>>(counts, cursor, bsum);
    scan2<<<1, 256, 0, stream>>>(bsum);
    scan3<<<SCANB, 1024, 0, stream>>>(counts, bsum, bp, cursor);
    scatter_kernel<<<(NNZ_ + 255) / 256, 256, 0, stream>>>(rows, cols, vals, cursor, edges);
    prep_kernel<<<20096, 256, 0, stream>>>(x, (uint_t*)X0, W, Wfrag);

    const int chebGrid = (N_V / 4) * 8;            // 40000 blocks: (rowgroup x 8 chunks)
    cheb_row<false><<<chebGrid, 256, 0, stream>>>(bp, edges, X0, nullptr, T1);
    cheb_row<true ><<<chebGrid, 256, 0, stream>>>(bp, edges, T1, X0, T2);
    cheb_row<true ><<<chebGrid, 256, 0, stream>>>(bp, edges, T2, T1, T3);
    cheb_row<true ><<<chebGrid, 256, 0, stream>>>(bp, edges, T3, T2, T4);
    cheb_row<true ><<<chebGrid, 256, 0, stream>>>(bp, edges, T4, T3, T5);

    fc_mfma<<<(N_V * B_) / 128, 256, 0, stream>>>(X0, T1, T2, T3, T4, T5, Wfrag, bias, out);
}

// Round 2
// 420.348 us; speedup vs baseline: 1.0777x; 1.0777x over previous
//
#include <hip/hip_runtime.h>

#define N_V  20000
#define B_   8
#define F_   64
#define K_   6
#define OUT_ 64
#define NNZ_ 320000
#define BF   512    // B_*F_
#define NBUK N_V                    // one bucket per row
#define SCANB 20                    // ceil(NBUK/1024)
#define EPAD (NNZ_ + N_V * 15)      // buckets padded to multiple of 16 edges

typedef unsigned short ushort_t;
typedef unsigned int   uint_t;

using frag_ab = __attribute__((ext_vector_type(8))) short;  // 8 bf16 (4 VGPRs)
using frag_cd = __attribute__((ext_vector_type(4))) float;  // 4 f32 acc

// ---- bf16 helpers ----
__device__ __forceinline__ ushort_t f2bf(float f) {          // round-to-nearest-even
    uint_t u = __float_as_uint(f);
    u += 0x7FFFu + ((u >> 16) & 1u);
    return (ushort_t)(u >> 16);
}
__device__ __forceinline__ uint_t pack2(float lo, float hi) {
    return (uint_t)f2bf(lo) | ((uint_t)f2bf(hi) << 16);
}
__device__ __forceinline__ void unpack2(uint_t u, float& lo, float& hi) {
    lo = __uint_as_float(u << 16);
    hi = __uint_as_float(u & 0xFFFF0000u);
}

// -------- bucketed build: one bucket per row, padded to multiple of 16 --------

__global__ void hist_kernel(const int* __restrict__ rows, int* __restrict__ counts) {
    int e = blockIdx.x * 256 + threadIdx.x;
    if (e < NNZ_) atomicAdd(&counts[rows[e]], 1);
}

__global__ __launch_bounds__(1024) void scan1(const int* __restrict__ counts,
                                              int* __restrict__ incl, int* __restrict__ bsum) {
    __shared__ int buf[1024];
    int tid = threadIdx.x;
    int i = blockIdx.x * 1024 + tid;
    int c = (i < NBUK) ? ((counts[i] + 15) & ~15) : 0;   // padded count
    buf[tid] = c;
    __syncthreads();
    for (int off = 1; off < 1024; off <<= 1) {
        int t = buf[tid];
        int add = (tid >= off) ? buf[tid - off] : 0;
        __syncthreads();
        buf[tid] = t + add;
        __syncthreads();
    }
    if (i < NBUK) incl[i] = buf[tid];
    if (tid == 1023) bsum[blockIdx.x] = buf[1023];
}

__global__ __launch_bounds__(256) void scan2(int* __restrict__ bsum) {
    __shared__ int buf[256];
    int tid = threadIdx.x;
    int c = (tid < SCANB) ? bsum[tid] : 0;
    buf[tid] = c;
    __syncthreads();
    for (int off = 1; off < 256; off <<= 1) {
        int t = buf[tid];
        int add = (tid >= off) ? buf[tid - off] : 0;
        __syncthreads();
        buf[tid] = t + add;
        __syncthreads();
    }
    if (tid < SCANB) bsum[tid] = buf[tid] - c;   // exclusive block offsets
}

__global__ __launch_bounds__(1024) void scan3(const int* __restrict__ counts,
                                              const int* __restrict__ bsum,
                                              int* __restrict__ bp, int* __restrict__ cursor) {
    int tid = threadIdx.x;
    int i = blockIdx.x * 1024 + tid;
    if (i < NBUK) {
        int pc = (counts[i] + 15) & ~15;
        int p = bsum[blockIdx.x] + cursor[i];   // global inclusive prefix (padded)
        bp[i + 1] = p;
        cursor[i] = p - pc;                     // bucket start for scatter
    }
    if (i == 0) bp[0] = 0;
}

// edges packed: {col, val_bits}; pad slots stay {0, 0.0f} from memset (zero contribution)
__global__ void scatter_kernel(const int* __restrict__ rows, const int* __restrict__ cols,
                               const float* __restrict__ vals, int* __restrict__ cursor,
                               int2* __restrict__ edges) {
    int e = blockIdx.x * 256 + threadIdx.x;
    if (e < NNZ_) {
        int pos = atomicAdd(&cursor[rows[e]], 1);
        edges[pos] = make_int2(cols[e], __float_as_int(vals[e]));
    }
}

// ---------------- fat prep: x->X0 bf16 (T layout [n][b][f]) + Wfrag pack ----------------
__global__ void prep_kernel(const float* __restrict__ x, uint_t* __restrict__ X0,
                            const float* __restrict__ W, ushort_t* __restrict__ Wfrag) {
    int blk = blockIdx.x;
    if (blk < 20000) {
        int idx = blk * 256 + threadIdx.x;      // over N_V*B_*32
        int f2 = idx & 31;
        int b  = (idx >> 5) & 7;
        int n  = idx >> 8;
        float2 v = *(const float2*)&x[((size_t)b * N_V + n) * F_ + f2 * 2];
        X0[n * 256 + b * 32 + f2] = pack2(v.x, v.y);
    } else {
        int idx = (blk - 20000) * 256 + threadIdx.x;
        if (idx < 12 * 4 * 64 * 8) {
            int j    = idx & 7;
            int lane = (idx >> 3) & 63;
            int ct   = (idx >> 9) & 3;
            int s    = idx >> 11;
            int o     = ct * 16 + (lane & 15);
            int kglob = s * 32 + ((lane >> 4) & 3) * 8 + j;
            Wfrag[idx] = f2bf(W[o * (K_ * F_) + kglob]);
        }
    }
}

// -------- SpMM: 2 rows per wave, 4 lane-groups x 4 edges in flight, chunked for XCD L2 --------
// chunk = blockIdx & 7 -> XCD affinity; per-XCD gather footprint = 2.56 MB (fits 4 MB L2).
// Group g (lanes 16g..16g+15) handles edge j+4g+q; lane covers 4 features (8B uint2 gather)
// -> one gather instruction moves 4 edges x 128B. Buckets padded to x16 with zero edges,
// so rows 2p,2p+1 form one contiguous 16-aligned stream with a single uniform boundary.
template <bool RECUR>
__global__ __launch_bounds__(256) void cheb_row2(const int* __restrict__ bp,
                                                 const int2* __restrict__ edges,
                                                 const ushort_t* __restrict__ Tprev,
                                                 const ushort_t* __restrict__ Tpp,
                                                 ushort_t* __restrict__ Tout) {
    const int wave = threadIdx.x >> 6, lane = threadIdx.x & 63;
    const int c    = blockIdx.x & 7;                   // chunk == batch index == XCD slot
    const int pair = (blockIdx.x >> 3) * 4 + wave;     // [0, 10000)
    const int r0   = pair * 2;
    const int g    = lane >> 4;                        // edge group 0..3
    const int f4   = (lane & 15) << 2;                 // 4 features per lane

    const int st  = bp[r0];
    const int mid = bp[r0 + 1];
    const int en  = bp[r0 + 2];

    const ushort_t* Tb = Tprev + (c << 6) + f4;        // + col*512 per edge
    const int2*    eb  = edges + g * 4;

    float a0 = 0.f, a1 = 0.f, a2 = 0.f, a3 = 0.f;      // row 2p
    float b0 = 0.f, b1 = 0.f, b2 = 0.f, b3 = 0.f;      // row 2p+1

    for (int j = st; j < en; j += 16) {
        const int4* ep = (const int4*)(eb + j);        // 16B-aligned (j,g*4 multiples)
        int4 Ea = ep[0];                               // edges q=0,1 of this group
        int4 Eb = ep[1];                               // edges q=2,3
        uint2 u0 = *(const uint2*)(Tb + ((size_t)Ea.x << 9));
        uint2 u1 = *(const uint2*)(Tb + ((size_t)Ea.z << 9));
        uint2 u2 = *(const uint2*)(Tb + ((size_t)Eb.x << 9));
        uint2 u3 = *(const uint2*)(Tb + ((size_t)Eb.z << 9));
        const float v0 = __int_as_float(Ea.y);
        const float v1 = __int_as_float(Ea.w);
        const float v2 = __int_as_float(Eb.y);
        const float v3 = __int_as_float(Eb.w);
        float e0, e1, e2, e3;
        if (j < mid) {                                 // wave-uniform branch
            unpack2(u0.x, e0, e1); unpack2(u0.y, e2, e3);
            a0 = fmaf(v0, e0, a0); a1 = fmaf(v0, e1, a1);
            a2 = fmaf(v0, e2, a2); a3 = fmaf(v0, e3, a3);
            unpack2(u1.x, e0, e1); unpack2(u1.y, e2, e3);
            a0 = fmaf(v1, e0, a0); a1 = fmaf(v1, e1, a1);
            a2 = fmaf(v1, e2, a2); a3 = fmaf(v1, e3, a3);
            unpack2(u2.x, e0, e1); unpack2(u2.y, e2, e3);
            a0 = fmaf(v2, e0, a0); a1 = fmaf(v2, e1, a1);
            a2 = fmaf(v2, e2, a2); a3 = fmaf(v2, e3, a3);
            unpack2(u3.x, e0, e1); unpack2(u3.y, e2, e3);
            a0 = fmaf(v3, e0, a0); a1 = fmaf(v3, e1, a1);
            a2 = fmaf(v3, e2, a2); a3 = fmaf(v3, e3, a3);
        } else {
            unpack2(u0.x, e0, e1); unpack2(u0.y, e2, e3);
            b0 = fmaf(v0, e0, b0); b1 = fmaf(v0, e1, b1);
            b2 = fmaf(v0, e2, b2); b3 = fmaf(v0, e3, b3);
            unpack2(u1.x, e0, e1); unpack2(u1.y, e2, e3);
            b0 = fmaf(v1, e0, b0); b1 = fmaf(v1, e1, b1);
            b2 = fmaf(v1, e2, b2); b3 = fmaf(v1, e3, b3);
            unpack2(u2.x, e0, e1); unpack2(u2.y, e2, e3);
            b0 = fmaf(v2, e0, b0); b1 = fmaf(v2, e1, b1);
            b2 = fmaf(v2, e2, b2); b3 = fmaf(v2, e3, b3);
            unpack2(u3.x, e0, e1); unpack2(u3.y, e2, e3);
            b0 = fmaf(v3, e0, b0); b1 = fmaf(v3, e1, b1);
            b2 = fmaf(v3, e2, b2); b3 = fmaf(v3, e3, b3);
        }
    }

    // cross-group reduction (4 groups hold partial sums of the same features)
    a0 += __shfl_xor(a0, 16, 64); a0 += __shfl_xor(a0, 32, 64);
    a1 += __shfl_xor(a1, 16, 64); a1 += __shfl_xor(a1, 32, 64);
    a2 += __shfl_xor(a2, 16, 64); a2 += __shfl_xor(a2, 32, 64);
    a3 += __shfl_xor(a3, 16, 64); a3 += __shfl_xor(a3, 32, 64);
    b0 += __shfl_xor(b0, 16, 64); b0 += __shfl_xor(b0, 32, 64);
    b1 += __shfl_xor(b1, 16, 64); b1 += __shfl_xor(b1, 32, 64);
    b2 += __shfl_xor(b2, 16, 64); b2 += __shfl_xor(b2, 32, 64);
    b3 += __shfl_xor(b3, 16, 64); b3 += __shfl_xor(b3, 32, 64);

    if (lane < 32) {
        float s0 = (lane < 16) ? a0 : b0;
        float s1 = (lane < 16) ? a1 : b1;
        float s2 = (lane < 16) ? a2 : b2;
        float s3 = (lane < 16) ? a3 : b3;
        const size_t o = (size_t)(r0 + (lane >> 4)) * BF + (c << 6) + f4;
        if (RECUR) {
            uint2 up = *(const uint2*)(Tpp + o);
            float p0, p1, p2, p3;
            unpack2(up.x, p0, p1); unpack2(up.y, p2, p3);
            s0 = fmaf(2.f, s0, -p0);
            s1 = fmaf(2.f, s1, -p1);
            s2 = fmaf(2.f, s2, -p2);
            s3 = fmaf(2.f, s3, -p3);
        }
        uint2 st2;
        st2.x = pack2(s0, s1);
        st2.y = pack2(s2, s3);
        *(uint2*)(Tout + o) = st2;
    }
}

// ---------------- FC via MFMA 16x16x32 bf16, 2 tiles/wave ----------------
__global__ __launch_bounds__(256) void fc_mfma(const ushort_t* __restrict__ X0,
                                               const ushort_t* __restrict__ T1,
                                               const ushort_t* __restrict__ T2,
                                               const ushort_t* __restrict__ T3,
                                               const ushort_t* __restrict__ T4,
                                               const ushort_t* __restrict__ T5,
                                               const ushort_t* __restrict__ Wfrag,
                                               const float* __restrict__ bias,
                                               float* __restrict__ out) {
    const int wave = threadIdx.x >> 6, lane = threadIdx.x & 63;
    const int quad = lane >> 4, col = lane & 15;
    const int tb = blockIdx.x * 128 + wave * 32;      // 2 tiles: tb, tb+16
    const int r0 = tb + col, r1 = tb + 16 + col;
    const ushort_t* Tbuf[6] = {X0, T1, T2, T3, T4, T5};

    frag_cd acc0[4], acc1[4];
#pragma unroll
    for (int ct = 0; ct < 4; ++ct) {
        acc0[ct] = (frag_cd){0.f, 0.f, 0.f, 0.f};
        acc1[ct] = (frag_cd){0.f, 0.f, 0.f, 0.f};
    }

#pragma unroll
    for (int s = 0; s < 12; ++s) {
        const int f0 = (s & 1) * 32 + quad * 8;
        frag_ab fa0 = *(const frag_ab*)(Tbuf[s >> 1] + (size_t)r0 * F_ + f0);
        frag_ab fa1 = *(const frag_ab*)(Tbuf[s >> 1] + (size_t)r1 * F_ + f0);
#pragma unroll
        for (int ct = 0; ct < 4; ++ct) {
            frag_ab bfr = *(const frag_ab*)(Wfrag + (((s * 4 + ct) * 64 + lane) << 3));
            acc0[ct] = __builtin_amdgcn_mfma_f32_16x16x32_bf16(fa0, bfr, acc0[ct], 0, 0, 0);
            acc1[ct] = __builtin_amdgcn_mfma_f32_16x16x32_bf16(fa1, bfr, acc1[ct], 0, 0, 0);
        }
    }

    // C/D: col = lane&15, row = quad*4 + reg
#pragma unroll
    for (int ct = 0; ct < 4; ++ct) {
        const int o = ct * 16 + col;
        const float bv = bias[o];
#pragma unroll
        for (int reg = 0; reg < 4; ++reg) {
            int ra = tb + quad * 4 + reg;
            int rb = ra + 16;
            out[(size_t)(ra & 7) * N_V * OUT_ + (size_t)(ra >> 3) * OUT_ + o] = acc0[ct][reg] + bv;
            out[(size_t)(rb & 7) * N_V * OUT_ + (size_t)(rb >> 3) * OUT_ + o] = acc1[ct][reg] + bv;
        }
    }
}

// ---------------- launcher ----------------

extern "C" void kernel_launch(void* const* d_in, const int* in_sizes, int n_in,
                              void* d_out, int out_size, void* d_ws, size_t ws_size,
                              hipStream_t stream) {
    const float* x    = (const float*)d_in[0];
    const int*   rows = (const int*)  d_in[1];
    const int*   cols = (const int*)  d_in[2];
    const float* vals = (const float*)d_in[3];
    const float* W    = (const float*)d_in[4];
    const float* bias = (const float*)d_in[5];
    float* out = (float*)d_out;

    const size_t TSZ = (size_t)N_V * BF;           // bf16 elements per T buffer
    ushort_t* T1 = (ushort_t*)d_ws;
    ushort_t* T2 = T1 + TSZ;
    ushort_t* T3 = T2 + TSZ;
    ushort_t* T4 = T3 + TSZ;
    ushort_t* T5 = T4 + TSZ;
    ushort_t* X0 = T5 + TSZ;
    ushort_t* Wfrag = X0 + TSZ;                    // 24576 ushorts
    int* counts    = (int*)(Wfrag + 24576);        // NBUK
    int* bp        = counts + NBUK;                // NBUK+1 (+pad)
    int* cursor    = bp + NBUK + 64;               // NBUK
    int* bsum      = cursor + NBUK;                // 256
    int2* edges    = (int2*)(bsum + 256);          // EPAD int2 (zero-padded)

    hipMemsetAsync(counts, 0, NBUK * sizeof(int), stream);
    hipMemsetAsync(edges, 0, (size_t)EPAD * sizeof(int2), stream);
    hist_kernel<<<(NNZ_ + 255) / 256, 256, 0, stream>>>(rows, counts);
    scan1<<<SCANB, 1024, 0, stream>>>(counts, cursor, bsum);
    scan2<<<1, 256, 0, stream>>>(bsum);
    scan3<<<SCANB, 1024, 0, stream>>>(counts, bsum, bp, cursor);
    scatter_kernel<<<(NNZ_ + 255) / 256, 256, 0, stream>>>(rows, cols, vals, cursor, edges);
    prep_kernel<<<20096, 256, 0, stream>>>(x, (uint_t*)X0, W, Wfrag);

    const int chebGrid = 2500 * 8;                 // (pairgroup of 4 waves) x 8 chunks
    cheb_row2<false><<<chebGrid, 256, 0, stream>>>(bp, edges, X0, nullptr, T1);
    cheb_row2<true ><<<chebGrid, 256, 0, stream>>>(bp, edges, T1, X0, T2);
    cheb_row2<true ><<<chebGrid, 256, 0, stream>>>(bp, edges, T2, T1, T3);
    cheb_row2<true ><<<chebGrid, 256, 0, stream>>>(bp, edges, T3, T2, T4);
    cheb_row2<true ><<<chebGrid, 256, 0, stream>>>(bp, edges, T4, T3, T5);

    fc_mfma<<<(N_V * B_) / 128, 256, 0, stream>>>(X0, T1, T2, T3, T4, T5, Wfrag, bias, out);
}

// Round 4
// 411.644 us; speedup vs baseline: 1.1005x; 1.0211x over previous
//
#include <hip/hip_runtime.h>

#define N_V  20000
#define B_   8
#define F_   64
#define K_   6
#define OUT_ 64
#define NNZ_ 320000
#define BF   512    // B_*F_
#define NBUK N_V                    // one bucket per row
#define SCANB 20                    // ceil(NBUK/1024)
#define EPAD (NNZ_ + N_V * 15)      // buckets padded to multiple of 16 edges

typedef unsigned short ushort_t;
typedef unsigned int   uint_t;

using frag_ab = __attribute__((ext_vector_type(8))) short;  // 8 bf16 (4 VGPRs)
using frag_cd = __attribute__((ext_vector_type(4))) float;  // 4 f32 acc

// ---- bf16 helpers ----
__device__ __forceinline__ ushort_t f2bf(float f) {          // round-to-nearest-even
    uint_t u = __float_as_uint(f);
    u += 0x7FFFu + ((u >> 16) & 1u);
    return (ushort_t)(u >> 16);
}
__device__ __forceinline__ uint_t pack2(float lo, float hi) {
    return (uint_t)f2bf(lo) | ((uint_t)f2bf(hi) << 16);
}
__device__ __forceinline__ void unpack2(uint_t u, float& lo, float& hi) {
    lo = __uint_as_float(u << 16);
    hi = __uint_as_float(u & 0xFFFF0000u);
}

// -------- bucketed build: one bucket per row, padded to multiple of 16 --------

__global__ void hist_kernel(const int* __restrict__ rows, int* __restrict__ counts) {
    int e = blockIdx.x * 256 + threadIdx.x;
    if (e < NNZ_) atomicAdd(&counts[rows[e]], 1);
}

__global__ __launch_bounds__(1024) void scan1(const int* __restrict__ counts,
                                              int* __restrict__ incl, int* __restrict__ bsum) {
    __shared__ int buf[1024];
    int tid = threadIdx.x;
    int i = blockIdx.x * 1024 + tid;
    int c = (i < NBUK) ? ((counts[i] + 15) & ~15) : 0;   // padded count
    buf[tid] = c;
    __syncthreads();
    for (int off = 1; off < 1024; off <<= 1) {
        int t = buf[tid];
        int add = (tid >= off) ? buf[tid - off] : 0;
        __syncthreads();
        buf[tid] = t + add;
        __syncthreads();
    }
    if (i < NBUK) incl[i] = buf[tid];
    if (tid == 1023) bsum[blockIdx.x] = buf[1023];
}

__global__ __launch_bounds__(256) void scan2(int* __restrict__ bsum) {
    __shared__ int buf[256];
    int tid = threadIdx.x;
    int c = (tid < SCANB) ? bsum[tid] : 0;
    buf[tid] = c;
    __syncthreads();
    for (int off = 1; off < 256; off <<= 1) {
        int t = buf[tid];
        int add = (tid >= off) ? buf[tid - off] : 0;
        __syncthreads();
        buf[tid] = t + add;
        __syncthreads();
    }
    if (tid < SCANB) bsum[tid] = buf[tid] - c;   // exclusive block offsets
}

__global__ __launch_bounds__(1024) void scan3(const int* __restrict__ counts,
                                              const int* __restrict__ bsum,
                                              int* __restrict__ bp, int* __restrict__ cursor) {
    int tid = threadIdx.x;
    int i = blockIdx.x * 1024 + tid;
    if (i < NBUK) {
        int pc = (counts[i] + 15) & ~15;
        int p = bsum[blockIdx.x] + cursor[i];   // global inclusive prefix (padded)
        bp[i + 1] = p;
        cursor[i] = p - pc;                     // bucket start for scatter
    }
    if (i == 0) bp[0] = 0;
}

// edges packed: {col, val_bits}; pad slots stay {0, 0.0f} from memset (zero contribution)
__global__ void scatter_kernel(const int* __restrict__ rows, const int* __restrict__ cols,
                               const float* __restrict__ vals, int* __restrict__ cursor,
                               int2* __restrict__ edges) {
    int e = blockIdx.x * 256 + threadIdx.x;
    if (e < NNZ_) {
        int pos = atomicAdd(&cursor[rows[e]], 1);
        edges[pos] = make_int2(cols[e], __float_as_int(vals[e]));
    }
}

// ---------------- fat prep: x->X0 bf16 (T layout [n][b][f]) + Wfrag pack ----------------
__global__ void prep_kernel(const float* __restrict__ x, uint_t* __restrict__ X0,
                            const float* __restrict__ W, ushort_t* __restrict__ Wfrag) {
    int blk = blockIdx.x;
    if (blk < 20000) {
        int idx = blk * 256 + threadIdx.x;      // over N_V*B_*32
        int f2 = idx & 31;
        int b  = (idx >> 5) & 7;
        int n  = idx >> 8;
        float2 v = *(const float2*)&x[((size_t)b * N_V + n) * F_ + f2 * 2];
        X0[n * 256 + b * 32 + f2] = pack2(v.x, v.y);
    } else {
        int idx = (blk - 20000) * 256 + threadIdx.x;
        if (idx < 12 * 4 * 64 * 8) {
            int j    = idx & 7;
            int lane = (idx >> 3) & 63;
            int ct   = (idx >> 9) & 3;
            int s    = idx >> 11;
            int o     = ct * 16 + (lane & 15);
            int kglob = s * 32 + ((lane >> 4) & 3) * 8 + j;
            Wfrag[idx] = f2bf(W[o * (K_ * F_) + kglob]);
        }
    }
}

// -------- SpMM: 2 rows/wave, 4 lane-groups x 4 edges, XCD-chunked, SW-pipelined --------
// chunk = blockIdx & 7 -> XCD affinity; per-XCD gather footprint = 2.56 MB (fits 4 MB L2).
// Pipeline: edges prefetched 2 iterations ahead; gathers for iter i+1 issued BEFORE the
// FMAs of iter i consume their data -> FMA wait is vmcnt(6), gather latency hidden.
template <bool RECUR>
__global__ __launch_bounds__(256) void cheb_row2(const int* __restrict__ bp,
                                                 const int2* __restrict__ edges,
                                                 const ushort_t* __restrict__ Tprev,
                                                 const ushort_t* __restrict__ Tpp,
                                                 ushort_t* __restrict__ Tout) {
    const int wave = threadIdx.x >> 6, lane = threadIdx.x & 63;
    const int c    = blockIdx.x & 7;                   // chunk == batch index == XCD slot
    const int pair = (blockIdx.x >> 3) * 4 + wave;     // [0, 10000)
    const int r0   = pair * 2;
    const int g    = lane >> 4;                        // edge group 0..3
    const int f4   = (lane & 15) << 2;                 // 4 features per lane

    const int st  = bp[r0];
    const int mid = bp[r0 + 1];
    const int en  = bp[r0 + 2];

    const ushort_t* Tb = Tprev + (c << 6) + f4;        // + col*512 per edge
    const int2*    eb  = edges + g * 4;

    float a0 = 0.f, a1 = 0.f, a2 = 0.f, a3 = 0.f;      // row 2p
    float b0 = 0.f, b1 = 0.f, b2 = 0.f, b3 = 0.f;      // row 2p+1

    auto consume = [&](int jj, const int4& A, const int4& Bv,
                       uint2 u0, uint2 u1, uint2 u2, uint2 u3) {
        const float v0 = __int_as_float(A.y);
        const float v1 = __int_as_float(A.w);
        const float v2 = __int_as_float(Bv.y);
        const float v3 = __int_as_float(Bv.w);
        float e0, e1, e2, e3;
        if (jj < mid) {                                // wave-uniform branch
            unpack2(u0.x, e0, e1); unpack2(u0.y, e2, e3);
            a0 = fmaf(v0, e0, a0); a1 = fmaf(v0, e1, a1);
            a2 = fmaf(v0, e2, a2); a3 = fmaf(v0, e3, a3);
            unpack2(u1.x, e0, e1); unpack2(u1.y, e2, e3);
            a0 = fmaf(v1, e0, a0); a1 = fmaf(v1, e1, a1);
            a2 = fmaf(v1, e2, a2); a3 = fmaf(v1, e3, a3);
            unpack2(u2.x, e0, e1); unpack2(u2.y, e2, e3);
            a0 = fmaf(v2, e0, a0); a1 = fmaf(v2, e1, a1);
            a2 = fmaf(v2, e2, a2); a3 = fmaf(v2, e3, a3);
            unpack2(u3.x, e0, e1); unpack2(u3.y, e2, e3);
            a0 = fmaf(v3, e0, a0); a1 = fmaf(v3, e1, a1);
            a2 = fmaf(v3, e2, a2); a3 = fmaf(v3, e3, a3);
        } else {
            unpack2(u0.x, e0, e1); unpack2(u0.y, e2, e3);
            b0 = fmaf(v0, e0, b0); b1 = fmaf(v0, e1, b1);
            b2 = fmaf(v0, e2, b2); b3 = fmaf(v0, e3, b3);
            unpack2(u1.x, e0, e1); unpack2(u1.y, e2, e3);
            b0 = fmaf(v1, e0, b0); b1 = fmaf(v1, e1, b1);
            b2 = fmaf(v1, e2, b2); b3 = fmaf(v1, e3, b3);
            unpack2(u2.x, e0, e1); unpack2(u2.y, e2, e3);
            b0 = fmaf(v2, e0, b0); b1 = fmaf(v2, e1, b1);
            b2 = fmaf(v2, e2, b2); b3 = fmaf(v2, e3, b3);
            unpack2(u3.x, e0, e1); unpack2(u3.y, e2, e3);
            b0 = fmaf(v3, e0, b0); b1 = fmaf(v3, e1, b1);
            b2 = fmaf(v3, e2, b2); b3 = fmaf(v3, e3, b3);
        }
    };

    if (st < en) {
        int4 A0, B0, A1, B1;
        uint2 c0, c1, c2, c3;
        {   // iter-0 edges
            const int4* p = (const int4*)(eb + st);
            A0 = p[0]; B0 = p[1];
        }
        {   // iter-1 edges (clamped; harmless redundant load at tail)
            const int jn = min(st + 16, en - 16);
            const int4* p = (const int4*)(eb + jn);
            A1 = p[0]; B1 = p[1];
        }
        // iter-0 gathers
        c0 = *(const uint2*)(Tb + ((size_t)A0.x << 9));
        c1 = *(const uint2*)(Tb + ((size_t)A0.z << 9));
        c2 = *(const uint2*)(Tb + ((size_t)B0.x << 9));
        c3 = *(const uint2*)(Tb + ((size_t)B0.z << 9));

        int j = st;
        for (; j + 16 < en; j += 16) {
            // issue next-iter gathers (edge data already resident)
            uint2 n0 = *(const uint2*)(Tb + ((size_t)A1.x << 9));
            uint2 n1 = *(const uint2*)(Tb + ((size_t)A1.z << 9));
            uint2 n2 = *(const uint2*)(Tb + ((size_t)B1.x << 9));
            uint2 n3 = *(const uint2*)(Tb + ((size_t)B1.z << 9));
            // prefetch edges 2 iterations ahead (clamped)
            int4 A2, B2;
            {
                const int jn = min(j + 32, en - 16);
                const int4* p = (const int4*)(eb + jn);
                A2 = p[0]; B2 = p[1];
            }
            // consume current (waits only on c*, 6 younger vmem ops stay in flight)
            consume(j, A0, B0, c0, c1, c2, c3);
            A0 = A1; B0 = B1; A1 = A2; B1 = B2;
            c0 = n0; c1 = n1; c2 = n2; c3 = n3;
        }
        consume(j, A0, B0, c0, c1, c2, c3);
    }

    // cross-group reduction (4 groups hold partial sums of the same features)
    a0 += __shfl_xor(a0, 16, 64); a0 += __shfl_xor(a0, 32, 64);
    a1 += __shfl_xor(a1, 16, 64); a1 += __shfl_xor(a1, 32, 64);
    a2 += __shfl_xor(a2, 16, 64); a2 += __shfl_xor(a2, 32, 64);
    a3 += __shfl_xor(a3, 16, 64); a3 += __shfl_xor(a3, 32, 64);
    b0 += __shfl_xor(b0, 16, 64); b0 += __shfl_xor(b0, 32, 64);
    b1 += __shfl_xor(b1, 16, 64); b1 += __shfl_xor(b1, 32, 64);
    b2 += __shfl_xor(b2, 16, 64); b2 += __shfl_xor(b2, 32, 64);
    b3 += __shfl_xor(b3, 16, 64); b3 += __shfl_xor(b3, 32, 64);

    if (lane < 32) {
        float s0 = (lane < 16) ? a0 : b0;
        float s1 = (lane < 16) ? a1 : b1;
        float s2 = (lane < 16) ? a2 : b2;
        float s3 = (lane < 16) ? a3 : b3;
        const size_t o = (size_t)(r0 + (lane >> 4)) * BF + (c << 6) + f4;
        if (RECUR) {
            uint2 up = *(const uint2*)(Tpp + o);
            float p0, p1, p2, p3;
            unpack2(up.x, p0, p1); unpack2(up.y, p2, p3);
            s0 = fmaf(2.f, s0, -p0);
            s1 = fmaf(2.f, s1, -p1);
            s2 = fmaf(2.f, s2, -p2);
            s3 = fmaf(2.f, s3, -p3);
        }
        uint2 st2;
        st2.x = pack2(s0, s1);
        st2.y = pack2(s2, s3);
        *(uint2*)(Tout + o) = st2;
    }
}

// ---------------- FC via MFMA 16x16x32 bf16, 2 tiles/wave ----------------
__global__ __launch_bounds__(256) void fc_mfma(const ushort_t* __restrict__ X0,
                                               const ushort_t* __restrict__ T1,
                                               const ushort_t* __restrict__ T2,
                                               const ushort_t* __restrict__ T3,
                                               const ushort_t* __restrict__ T4,
                                               const ushort_t* __restrict__ T5,
                                               const ushort_t* __restrict__ Wfrag,
                                               const float* __restrict__ bias,
                                               float* __restrict__ out) {
    const int wave = threadIdx.x >> 6, lane = threadIdx.x & 63;
    const int quad = lane >> 4, col = lane & 15;
    const int tb = blockIdx.x * 128 + wave * 32;      // 2 tiles: tb, tb+16
    const int r0 = tb + col, r1 = tb + 16 + col;
    const ushort_t* Tbuf[6] = {X0, T1, T2, T3, T4, T5};

    frag_cd acc0[4], acc1[4];
#pragma unroll
    for (int ct = 0; ct < 4; ++ct) {
        acc0[ct] = (frag_cd){0.f, 0.f, 0.f, 0.f};
        acc1[ct] = (frag_cd){0.f, 0.f, 0.f, 0.f};
    }

#pragma unroll
    for (int s = 0; s < 12; ++s) {
        const int f0 = (s & 1) * 32 + quad * 8;
        frag_ab fa0 = *(const frag_ab*)(Tbuf[s >> 1] + (size_t)r0 * F_ + f0);
        frag_ab fa1 = *(const frag_ab*)(Tbuf[s >> 1] + (size_t)r1 * F_ + f0);
#pragma unroll
        for (int ct = 0; ct < 4; ++ct) {
            frag_ab bfr = *(const frag_ab*)(Wfrag + (((s * 4 + ct) * 64 + lane) << 3));
            acc0[ct] = __builtin_amdgcn_mfma_f32_16x16x32_bf16(fa0, bfr, acc0[ct], 0, 0, 0);
            acc1[ct] = __builtin_amdgcn_mfma_f32_16x16x32_bf16(fa1, bfr, acc1[ct], 0, 0, 0);
        }
    }

    // C/D: col = lane&15, row = quad*4 + reg
#pragma unroll
    for (int ct = 0; ct < 4; ++ct) {
        const int o = ct * 16 + col;
        const float bv = bias[o];
#pragma unroll
        for (int reg = 0; reg < 4; ++reg) {
            int ra = tb + quad * 4 + reg;
            int rb = ra + 16;
            out[(size_t)(ra & 7) * N_V * OUT_ + (size_t)(ra >> 3) * OUT_ + o] = acc0[ct][reg] + bv;
            out[(size_t)(rb & 7) * N_V * OUT_ + (size_t)(rb >> 3) * OUT_ + o] = acc1[ct][reg] + bv;
        }
    }
}

// ---------------- launcher ----------------

extern "C" void kernel_launch(void* const* d_in, const int* in_sizes, int n_in,
                              void* d_out, int out_size, void* d_ws, size_t ws_size,
                              hipStream_t stream) {
    const float* x    = (const float*)d_in[0];
    const int*   rows = (const int*)  d_in[1];
    const int*   cols = (const int*)  d_in[2];
    const float* vals = (const float*)d_in[3];
    const float* W    = (const float*)d_in[4];
    const float* bias = (const float*)d_in[5];
    float* out = (float*)d_out;

    const size_t TSZ = (size_t)N_V * BF;           // bf16 elements per T buffer
    ushort_t* T1 = (ushort_t*)d_ws;
    ushort_t* T2 = T1 + TSZ;
    ushort_t* T3 = T2 + TSZ;
    ushort_t* T4 = T3 + TSZ;
    ushort_t* T5 = T4 + TSZ;
    ushort_t* X0 = T5 + TSZ;
    ushort_t* Wfrag = X0 + TSZ;                    // 24576 ushorts
    int* counts    = (int*)(Wfrag + 24576);        // NBUK
    int* bp        = counts + NBUK;                // NBUK+1 (+pad)
    int* cursor    = bp + NBUK + 64;               // NBUK
    int* bsum      = cursor + NBUK;                // 256
    int2* edges    = (int2*)(bsum + 256);          // EPAD int2 (zero-padded)

    hipMemsetAsync(counts, 0, NBUK * sizeof(int), stream);
    hipMemsetAsync(edges, 0, (size_t)EPAD * sizeof(int2), stream);
    hist_kernel<<<(NNZ_ + 255) / 256, 256, 0, stream>>>(rows, counts);
    scan1<<<SCANB, 1024, 0, stream>>>(counts, cursor, bsum);
    scan2<<<1, 256, 0, stream>>>(bsum);
    scan3<<<SCANB, 1024, 0, stream>>>(counts, bsum, bp, cursor);
    scatter_kernel<<<(NNZ_ + 255) / 256, 256, 0, stream>>>(rows, cols, vals, cursor, edges);
    prep_kernel<<<20096, 256, 0, stream>>>(x, (uint_t*)X0, W, Wfrag);

    const int chebGrid = 2500 * 8;                 // (pairgroup of 4 waves) x 8 chunks
    cheb_row2<false><<<chebGrid, 256, 0, stream>>>(bp, edges, X0, nullptr, T1);
    cheb_row2<true ><<<chebGrid, 256, 0, stream>>>(bp, edges, T1, X0, T2);
    cheb_row2<true ><<<chebGrid, 256, 0, stream>>>(bp, edges, T2, T1, T3);
    cheb_row2<true ><<<chebGrid, 256, 0, stream>>>(bp, edges, T3, T2, T4);
    cheb_row2<true ><<<chebGrid, 256, 0, stream>>>(bp, edges, T4, T3, T5);

    fc_mfma<<<(N_V * B_) / 128, 256, 0, stream>>>(X0, T1, T2, T3, T4, T5, Wfrag, bias, out);
}